// Round 3
// baseline (224.015 us; speedup 1.0000x reference)
//
#include <hip/hip_runtime.h>

// AttentionSinkRope — fused f32 shifted-copy + constant-angle re-rotation.
//
//   k_caches: [128 lh][128 d][4064 pos]   (pos contiguous)
//   v_caches: [128 lh][4064 pos][128 d]   (d contiguous)
//   out = new_k ++ new_v (float32)
//
// rerotation tables are position-independent (angle = -SHIFT*theta_d) ->
// row 0 supplies the 64 (C,S) pairs. Keep-region shift is a constant
// element offset: +128 within a K row, +16384 for V.
//
// Single kernel, 2048 blocks x 256. Two grid-stride phases over pow2-padded
// unit spaces (decode = shifts/masks only):
//   K phase: 2^23 units = (lh*64+d) x 1024 chunks  (chunk = float4, 2 rows/unit)
//   V phase: 2^24 units = (lh*4096+row_pad) x 32 chunks
// Waves flow from K phase into V phase with no dispatch boundary.

#define KELEMS 66584576ull   // 128 * 128 * 4064

__global__ __launch_bounds__(256) void sinkrope_fused(
    const float* __restrict__ k,
    const float* __restrict__ v,
    const float* __restrict__ rcos,
    const float* __restrict__ rsin,
    float* __restrict__ outk,
    float* __restrict__ outv)
{
    const unsigned int tid = blockIdx.x * 256u + threadIdx.x;   // < 2^19

    // ---------------- K phase: 16 x 2^19 = 2^23 units ----------------
    #pragma unroll 2
    for (unsigned int it = 0; it < 16; ++it) {
        const unsigned int i = tid + (it << 19);
        const unsigned int c = i & 1023u;          // float4 chunk in row
        if (c >= 1016u) continue;                  // row pad (1016 real)
        const unsigned int pr = i >> 10;           // lh*64 + d, < 8192
        // paired rows 2d, 2d+1 of (lh): global row = 2*pr
        const size_t baseA = ((size_t)(pr << 1) << 12) - ((size_t)(pr << 1) << 5); // *4064
        const float* srcA = k + baseA;
        const float* srcB = srcA + 4064;
        float*       dstA = outk + baseA;
        float*       dstB = dstA + 4064;
        const int c0 = c << 2;
        if (c >= 984u) {                           // evicted tail: zeros
            float4 z = make_float4(0.f, 0.f, 0.f, 0.f);
            *(float4*)(dstA + c0) = z;
            *(float4*)(dstB + c0) = z;
        } else if (c == 0u) {                      // sink cols 0..3: copy
            *(float4*)(dstA) = *(const float4*)(srcA);
            *(float4*)(dstB) = *(const float4*)(srcB);
        } else {                                   // keep: rotate, src +128
            const float C = rcos[pr & 63u];        // wave-uniform broadcast
            const float S = rsin[pr & 63u];
            float4 a = *(const float4*)(srcA + c0 + 128);
            float4 b = *(const float4*)(srcB + c0 + 128);
            float4 oa, ob;
            oa.x = a.x * C - b.x * S;  ob.x = a.x * S + b.x * C;
            oa.y = a.y * C - b.y * S;  ob.y = a.y * S + b.y * C;
            oa.z = a.z * C - b.z * S;  ob.z = a.z * S + b.z * C;
            oa.w = a.w * C - b.w * S;  ob.w = a.w * S + b.w * C;
            *(float4*)(dstA + c0) = oa;
            *(float4*)(dstB + c0) = ob;
        }
    }

    // ---------------- V phase: 32 x 2^19 = 2^24 units ----------------
    #pragma unroll 2
    for (unsigned int it = 0; it < 32; ++it) {
        const unsigned int j = tid + (it << 19);
        const unsigned int c     = j & 31u;        // float4 chunk in row
        const unsigned int rowid = j >> 5;         // lh*4096 + row_pad
        const unsigned int row   = rowid & 4095u;
        if (row >= 4064u) continue;                // lh pad (4064 real)
        const unsigned int lh    = rowid >> 12;
        const size_t off = ((size_t)lh * 520192u) + ((size_t)row << 7) + (c << 2);
        float4 val;
        if (row < 4u) {                            // sink rows
            val = *(const float4*)(v + off);
        } else if (row < 3936u) {                  // keep: src +128 rows
            val = *(const float4*)(v + off + 16384);
        } else {                                   // evicted tail
            val = make_float4(0.f, 0.f, 0.f, 0.f);
        }
        *(float4*)(outv + off) = val;
    }
}

extern "C" void kernel_launch(void* const* d_in, const int* in_sizes, int n_in,
                              void* d_out, int out_size, void* d_ws, size_t ws_size,
                              hipStream_t stream) {
    const float* k  = (const float*)d_in[0];
    const float* v  = (const float*)d_in[1];
    const float* rc = (const float*)d_in[2];
    const float* rs = (const float*)d_in[3];
    float* outk = (float*)d_out;
    float* outv = outk + KELEMS;

    hipLaunchKernelGGL(sinkrope_fused, dim3(2048), dim3(256), 0, stream,
                       k, v, rc, rs, outk, outv);
}

// Round 5
// 177.757 us; speedup vs baseline: 1.2602x; 1.2602x over previous
//
#include <hip/hip_runtime.h>

// AttentionSinkRope — f32 shifted-copy + constant-angle re-rotation.
// Round-2 structure (best: 193 us) + nontemporal loads/stores (single lever).
// nt builtins need native vector types, not HIP_vector_type -> ext_vector f4.
//
//   k_caches: [128 lh][128 d][4064 pos]   (pos contiguous)
//   v_caches: [128 lh][4064 pos][128 d]   (d contiguous)
//   rerotation_cos/sin: [3932][64]        (all rows identical)
//   out = new_k ++ new_v (float32)

#define LH      128
#define DDIM    128
#define CLEN    4064
#define SINKN   4
#define KEEPEND 3936
#define SHIFT   128
#define KELEMS  66584576ull   // LH * DDIM * CLEN

typedef float f4 __attribute__((ext_vector_type(4)));

__device__ __forceinline__ f4 ntload4(const float* p) {
    return __builtin_nontemporal_load((const f4*)p);
}
__device__ __forceinline__ void ntstore4(float* p, f4 v) {
    __builtin_nontemporal_store(v, (f4*)p);
}

// grid (64 d-pairs, 128 lh), block 256. Each block: rows 2d, 2d+1 of one
// (layer,head); positions contiguous -> coalesced float4.
__global__ __launch_bounds__(256) void k_rope_kernel(
    const float* __restrict__ k,
    const float* __restrict__ rcos,
    const float* __restrict__ rsin,
    float* __restrict__ out)
{
    const int rp = blockIdx.x;           // head-dim pair d
    const int lh = blockIdx.y;
    const size_t rowA = (size_t)lh * ((size_t)DDIM * CLEN) + (size_t)(2 * rp) * CLEN;
    const float* srcA = k + rowA;
    const float* srcB = srcA + CLEN;
    float* dstA = out + rowA;
    float* dstB = dstA + CLEN;

    const float C = rcos[rp];            // table rows identical -> row 0
    const float S = rsin[rp];

    for (int chunk = threadIdx.x; chunk < 1016; chunk += 256) {
        const int c0 = chunk * 4;
        if (chunk >= 984) {
            f4 z = (f4)0.f;
            ntstore4(dstA + c0, z);
            ntstore4(dstB + c0, z);
        } else if (chunk == 0) {
            ntstore4(dstA, ntload4(srcA));
            ntstore4(dstB, ntload4(srcB));
        } else {
            f4 a = ntload4(srcA + c0 + SHIFT);
            f4 b = ntload4(srcB + c0 + SHIFT);
            f4 oa = a * C - b * S;
            f4 ob = a * S + b * C;
            ntstore4(dstA + c0, oa);
            ntstore4(dstB + c0, ob);
        }
    }
}

// grid (508, 128), block 256. One float4 per thread; keep shift = +16384 elems.
__global__ __launch_bounds__(256) void v_copy_kernel(
    const float* __restrict__ v,
    float* __restrict__ out)
{
    const int lh = blockIdx.y;
    const size_t base = (size_t)lh * ((size_t)CLEN * DDIM);
    const int idx = blockIdx.x * 256 + threadIdx.x;
    const int row = idx >> 5;            // 32 chunks per row
    const size_t off = base + (size_t)idx * 4;
    f4 val;
    if (row < SINKN) {
        val = ntload4(v + off);
    } else if (row < KEEPEND) {
        val = ntload4(v + off + (size_t)SHIFT * DDIM);
    } else {
        val = (f4)0.f;
    }
    ntstore4(out + off, val);
}

extern "C" void kernel_launch(void* const* d_in, const int* in_sizes, int n_in,
                              void* d_out, int out_size, void* d_ws, size_t ws_size,
                              hipStream_t stream) {
    const float* k  = (const float*)d_in[0];
    const float* v  = (const float*)d_in[1];
    const float* rc = (const float*)d_in[2];
    const float* rs = (const float*)d_in[3];
    float* outk = (float*)d_out;
    float* outv = outk + KELEMS;

    hipLaunchKernelGGL(k_rope_kernel, dim3(64, 128), dim3(256), 0, stream,
                       k, rc, rs, outk);
    hipLaunchKernelGGL(v_copy_kernel, dim3(508, 128), dim3(256), 0, stream,
                       v, outv);
}